// Round 4
// baseline (977.767 us; speedup 1.0000x reference)
//
#include <hip/hip_runtime.h>
#include <hip/hip_bf16.h>

// Problem: CliffordEPBottleneck — 10 relaxation steps of
//   rho = tanh(h); drive = W_sym @ rho + x; h = 0.9h + 0.1(1-rho^2)*drive
// B=256, nodes=4096, COMP=4. Core cost: 10x GEMM (1024 x 4096 x 4096) in bf16 MFMA.
//
// R4 change: raise FLOP per LDS-byte. 64x64 per-wave tile (4x4 acc of
// 16x16x32), BM=BN=128, grid 256 (1 block/CU, 4 waves). 16 MFMA per 8
// ds_read_b128 (was 8 per 6). Single-barrier prefetch loop, unrolled 2x,
// staging offsets hoisted. R2/R3 showed: LDS pipe ~96k cyc/CU/step was the
// dominant term (all other pipes <= 23% busy).

#define BATCH   256
#define NODES   4096
#define MDIM    1024        // B*COMP
#define KDIM    4096
#define DLEN    16384       // NODES*COMP

typedef __attribute__((ext_vector_type(8))) __bf16 bf16x8;
typedef __attribute__((ext_vector_type(4))) float  f32x4;

static __device__ __forceinline__ unsigned short f32_to_bf16(float f) {
    unsigned int u = __float_as_uint(f);
    u += 0x7fffu + ((u >> 16) & 1u);   // round-to-nearest-even
    return (unsigned short)(u >> 16);
}

// ---------------------------------------------------------------------------
// Kernel 1: Wb[n][m] = bf16(0.5*(W[n][m] + W[m][n]))
// ---------------------------------------------------------------------------
__global__ __launch_bounds__(256)
void symw_kernel(const float* __restrict__ W, unsigned short* __restrict__ Wb) {
    __shared__ float Ta[64][64];
    __shared__ float Tb[64][65];   // +1 pad: transposed read below
    const int tn = blockIdx.y, tm = blockIdx.x;
    const int c  = threadIdx.x & 63;
    const int r0 = threadIdx.x >> 6;   // 0..3
#pragma unroll
    for (int rr = 0; rr < 16; ++rr) {
        int r = r0 * 16 + rr;
        Ta[r][c] = W[(size_t)(tn * 64 + r) * 4096 + tm * 64 + c];
        Tb[r][c] = W[(size_t)(tm * 64 + r) * 4096 + tn * 64 + c];
    }
    __syncthreads();
#pragma unroll
    for (int rr = 0; rr < 16; ++rr) {
        int r = r0 * 16 + rr;
        float v = 0.5f * (Ta[r][c] + Tb[c][r]);
        Wb[(size_t)(tn * 64 + r) * 4096 + tm * 64 + c] = f32_to_bf16(v);
    }
}

// ---------------------------------------------------------------------------
// Kernel 2: h = x ; R0[(b*4+c), m] = bf16(tanh(x[b, m*4+c]))
// ---------------------------------------------------------------------------
__global__ __launch_bounds__(256)
void init_kernel(const float* __restrict__ x, float* __restrict__ h,
                 unsigned short* __restrict__ R0) {
    int idx = blockIdx.x * blockDim.x + threadIdx.x;   // over B*NODES = 1M
    int b = idx >> 12;
    int m = idx & 4095;
    f32x4 xv = *(const f32x4*)(x + (size_t)idx * 4);
    *(f32x4*)(h + (size_t)idx * 4) = xv;
#pragma unroll
    for (int c = 0; c < 4; ++c) {
        R0[((size_t)(b * 4 + c)) * (size_t)KDIM + m] = f32_to_bf16(tanhf(xv[c]));
    }
}

// ---------------------------------------------------------------------------
// Kernel 3: one relaxation step. BM=BN=128, BK=64, 256 threads (4 waves 2x2),
// wave tile 64x64 = 4x4 fragments of 16x16x32 bf16 MFMA.
// global_load_lds width-16 staging, XOR-swizzled LDS (both sides),
// double-buffered, one s_barrier + vmcnt(0) per K-iter, loop unrolled 2x.
// ---------------------------------------------------------------------------
#define BM 128
#define BN 128
#define BK 64
#define NT (KDIM / BK)   // 64

__global__ __launch_bounds__(256, 1)
void step_kernel(const unsigned short* __restrict__ Rcur,
                 const unsigned short* __restrict__ Wb,
                 const float* __restrict__ x,
                 float* __restrict__ h,
                 unsigned short* __restrict__ Rnxt,
                 float* __restrict__ out) {
    __shared__ unsigned short As[2][BM * BK];   // 2 x 16 KB
    __shared__ unsigned short Bs[2][BN * BK];   // 2 x 16 KB

    const int tid  = threadIdx.x;
    const int bx   = blockIdx.x;           // n-tile (0..31)
    const int by   = blockIdx.y;           // m-tile (0..7)
    const int rowA0 = by * BM;
    const int rowB0 = bx * BN;

    const int w    = tid >> 6;              // 0..3
    const int lane = tid & 63;
    const int m0   = (w >> 1) * 64;
    const int n0   = (w & 1) * 64;
    const int lr   = lane & 15;
    const int lk   = lane >> 4;             // 0..3
    const int sw   = lr & 7;                // row&7 == lr&7 for all fragments

    // hoisted staging offsets: 4 A-chunks + 4 B-chunks per thread
    size_t offA[4], offB[4];
    int    ldso[4];
#pragma unroll
    for (int j = 0; j < 4; ++j) {
        int chunk = tid + 256 * j;           // 0..1023
        int row = chunk >> 3, cs = chunk & 7;
        int cg = cs ^ (row & 7);
        offA[j] = (size_t)(rowA0 + row) * KDIM + cg * 8;
        offB[j] = (size_t)(rowB0 + row) * KDIM + cg * 8;
        ldso[j] = chunk * 8;
    }

    f32x4 acc[4][4];
#pragma unroll
    for (int mi = 0; mi < 4; ++mi)
#pragma unroll
        for (int ni = 0; ni < 4; ++ni)
            acc[mi][ni] = (f32x4){0.f, 0.f, 0.f, 0.f};

#define STAGE(buf, k0)                                                           \
    do {                                                                         \
        _Pragma("unroll")                                                        \
        for (int j = 0; j < 4; ++j) {                                            \
            __builtin_amdgcn_global_load_lds(                                    \
                (const __attribute__((address_space(1))) void*)(Rcur + offA[j] + (k0)), \
                (__attribute__((address_space(3))) void*)(As[buf] + ldso[j]),    \
                16, 0, 0);                                                       \
        }                                                                        \
        _Pragma("unroll")                                                        \
        for (int j = 0; j < 4; ++j) {                                            \
            __builtin_amdgcn_global_load_lds(                                    \
                (const __attribute__((address_space(1))) void*)(Wb + offB[j] + (k0)), \
                (__attribute__((address_space(3))) void*)(Bs[buf] + ldso[j]),    \
                16, 0, 0);                                                       \
        }                                                                        \
    } while (0)

#define COMPUTE(buf)                                                             \
    do {                                                                         \
        _Pragma("unroll")                                                        \
        for (int kk = 0; kk < 2; ++kk) {                                         \
            bf16x8 a[4], b[4];                                                   \
            int slot = (kk * 4 + lk) ^ sw;                                       \
            _Pragma("unroll")                                                    \
            for (int mi = 0; mi < 4; ++mi)                                       \
                a[mi] = *(const bf16x8*)(As[buf] + (m0 + mi * 16 + lr) * BK + slot * 8); \
            _Pragma("unroll")                                                    \
            for (int ni = 0; ni < 4; ++ni)                                       \
                b[ni] = *(const bf16x8*)(Bs[buf] + (n0 + ni * 16 + lr) * BK + slot * 8); \
            _Pragma("unroll")                                                    \
            for (int mi = 0; mi < 4; ++mi)                                       \
                _Pragma("unroll")                                                \
                for (int ni = 0; ni < 4; ++ni)                                   \
                    acc[mi][ni] = __builtin_amdgcn_mfma_f32_16x16x32_bf16(       \
                        a[mi], b[ni], acc[mi][ni], 0, 0, 0);                     \
        }                                                                        \
    } while (0)

    // prologue: stage tile 0 into buf 0
    STAGE(0, 0);
    asm volatile("s_waitcnt vmcnt(0)" ::: "memory");
    __builtin_amdgcn_s_barrier();

    for (int t = 0; t < NT; t += 2) {
        if (t + 1 < NT) STAGE(1, (size_t)(t + 1) * BK);
        COMPUTE(0);
        asm volatile("s_waitcnt vmcnt(0)" ::: "memory");
        __builtin_amdgcn_s_barrier();
        if (t + 2 < NT) STAGE(0, (size_t)(t + 2) * BK);
        COMPUTE(1);
        asm volatile("s_waitcnt vmcnt(0)" ::: "memory");
        __builtin_amdgcn_s_barrier();
    }
#undef STAGE
#undef COMPUTE

    // Epilogue. C/D layout: col = lane&15, row = (lane>>4)*4 + reg.
    // One lane's 4 regs = c=0..3 of a single (b, n) -> contiguous float4 in h/x.
#pragma unroll
    for (int mi = 0; mi < 4; ++mi) {
        int i0 = rowA0 + m0 + mi * 16 + lk * 4;   // multiple of 4
        int b  = i0 >> 2;
#pragma unroll
        for (int ni = 0; ni < 4; ++ni) {
            int n = rowB0 + n0 + ni * 16 + lr;
            size_t hidx = (size_t)b * DLEN + (size_t)n * 4;
            f32x4 h4 = *(const f32x4*)(h + hidx);
            f32x4 x4 = *(const f32x4*)(x + hidx);
            f32x4 hn;
#pragma unroll
            for (int r = 0; r < 4; ++r) {
                float hv   = h4[r];
                float rho  = tanhf(hv);
                float drive = acc[mi][ni][r] + x4[r];
                float hnew = 0.9f * hv + 0.1f * (1.0f - rho * rho) * drive;
                hn[r] = hnew;
                Rnxt[(size_t)(i0 + r) * KDIM + n] = f32_to_bf16(tanhf(hnew));
            }
            *(f32x4*)(h + hidx) = hn;
            if (out) out[(size_t)b * NODES + n] = hn[0];
        }
    }
}

// ---------------------------------------------------------------------------
extern "C" void kernel_launch(void* const* d_in, const int* in_sizes, int n_in,
                              void* d_out, int out_size, void* d_ws, size_t ws_size,
                              hipStream_t stream) {
    const float* x = (const float*)d_in[0];   // (256, 16384) f32
    const float* W = (const float*)d_in[1];   // (4096, 4096) f32
    float* out = (float*)d_out;               // (256, 4096) f32

    char* ws = (char*)d_ws;
    // ws layout: Wb 32MB | R0 8MB | R1 8MB | h 16MB  (total 64MB)
    unsigned short* Wb = (unsigned short*)(ws);
    unsigned short* R0 = (unsigned short*)(ws + ((size_t)32 << 20));
    unsigned short* R1 = (unsigned short*)(ws + ((size_t)40 << 20));
    float*          h  = (float*)(ws + ((size_t)48 << 20));

    symw_kernel<<<dim3(64, 64), 256, 0, stream>>>(W, Wb);
    init_kernel<<<dim3(4096), 256, 0, stream>>>(x, h, R0);

    unsigned short* rc = R0;
    unsigned short* rn = R1;
    for (int s = 0; s < 10; ++s) {
        step_kernel<<<dim3(32, 8), 256, 0, stream>>>(
            rc, Wb, x, h, rn, (s == 9) ? out : nullptr);
        unsigned short* t = rc; rc = rn; rn = t;
    }
}

// Round 5
// 642.988 us; speedup vs baseline: 1.5207x; 1.5207x over previous
//
#include <hip/hip_runtime.h>
#include <hip/hip_bf16.h>

// Problem: CliffordEPBottleneck — 10 relaxation steps of
//   rho = tanh(h); drive = W_sym @ rho + x; h = 0.9h + 0.1(1-rho^2)*drive
// B=256, nodes=4096, COMP=4. Core cost: 10x GEMM (1024 x 4096 x 4096) in bf16 MFMA.
//
// R5: back to R2 geometry (BM=64 BN=128, 4 waves, grid 512 = 2 blk/CU — best
// measured). ONE change: T4 counted-vmcnt pipeline. 3-deep LDS ring,
// vmcnt(6) (not 0) + single raw s_barrier per K-iter; next tile's 6
// global_load_lds stay in flight across the barrier. R3/R4 lesson: never
// reduce blocks/CU below 2, never full-drain per iter.

#define BATCH   256
#define NODES   4096
#define MDIM    1024        // B*COMP
#define KDIM    4096
#define DLEN    16384       // NODES*COMP

typedef __attribute__((ext_vector_type(8))) __bf16 bf16x8;
typedef __attribute__((ext_vector_type(4))) float  f32x4;

static __device__ __forceinline__ unsigned short f32_to_bf16(float f) {
    unsigned int u = __float_as_uint(f);
    u += 0x7fffu + ((u >> 16) & 1u);   // round-to-nearest-even
    return (unsigned short)(u >> 16);
}

// ---------------------------------------------------------------------------
// Kernel 1: Wb[n][m] = bf16(0.5*(W[n][m] + W[m][n]))
// ---------------------------------------------------------------------------
__global__ __launch_bounds__(256)
void symw_kernel(const float* __restrict__ W, unsigned short* __restrict__ Wb) {
    __shared__ float Ta[64][64];
    __shared__ float Tb[64][65];   // +1 pad: transposed read below
    const int tn = blockIdx.y, tm = blockIdx.x;
    const int c  = threadIdx.x & 63;
    const int r0 = threadIdx.x >> 6;   // 0..3
#pragma unroll
    for (int rr = 0; rr < 16; ++rr) {
        int r = r0 * 16 + rr;
        Ta[r][c] = W[(size_t)(tn * 64 + r) * 4096 + tm * 64 + c];
        Tb[r][c] = W[(size_t)(tm * 64 + r) * 4096 + tn * 64 + c];
    }
    __syncthreads();
#pragma unroll
    for (int rr = 0; rr < 16; ++rr) {
        int r = r0 * 16 + rr;
        float v = 0.5f * (Ta[r][c] + Tb[c][r]);
        Wb[(size_t)(tn * 64 + r) * 4096 + tm * 64 + c] = f32_to_bf16(v);
    }
}

// ---------------------------------------------------------------------------
// Kernel 2: h = x ; R0[(b*4+c), m] = bf16(tanh(x[b, m*4+c]))
// ---------------------------------------------------------------------------
__global__ __launch_bounds__(256)
void init_kernel(const float* __restrict__ x, float* __restrict__ h,
                 unsigned short* __restrict__ R0) {
    int idx = blockIdx.x * blockDim.x + threadIdx.x;   // over B*NODES = 1M
    int b = idx >> 12;
    int m = idx & 4095;
    f32x4 xv = *(const f32x4*)(x + (size_t)idx * 4);
    *(f32x4*)(h + (size_t)idx * 4) = xv;
#pragma unroll
    for (int c = 0; c < 4; ++c) {
        R0[((size_t)(b * 4 + c)) * (size_t)KDIM + m] = f32_to_bf16(tanhf(xv[c]));
    }
}

// ---------------------------------------------------------------------------
// Kernel 3: one relaxation step. BM=64 BN=128 BK=64, 256 threads (4 waves),
// wave = 32x64 output, 16x16x32 bf16 MFMA, global_load_lds width-16 staging,
// XOR-swizzled LDS (both sides). 3-deep ring, counted vmcnt(6), one
// s_barrier per K-iter (no full drain in the main loop).
// ---------------------------------------------------------------------------
#define BM 64
#define BN 128
#define BK 64
#define NT (KDIM / BK)   // 64

__global__ __launch_bounds__(256, 2)
void step_kernel(const unsigned short* __restrict__ Rcur,
                 const unsigned short* __restrict__ Wb,
                 const float* __restrict__ x,
                 float* __restrict__ h,
                 unsigned short* __restrict__ Rnxt,
                 float* __restrict__ out) {
    __shared__ unsigned short As[3][BM * BK];   // 3 x 8 KB
    __shared__ unsigned short Bs[3][BN * BK];   // 3 x 16 KB  => 72 KB total

    const int tid  = threadIdx.x;
    const int bx   = blockIdx.x;           // n-tile (0..31)
    const int by   = blockIdx.y;           // m-tile (0..15)
    const int rowA0 = by * BM;
    const int rowB0 = bx * BN;

    const int w    = tid >> 6;
    const int lane = tid & 63;
    const int m0   = (w >> 1) * 32;
    const int n0   = (w & 1) * 64;
    const int lr   = lane & 15;
    const int lk   = lane >> 4;             // 0..3

    // hoisted staging offsets: 2 A-chunks + 4 B-chunks per thread
    size_t offA[2], offB[4];
    int ldsoA[2], ldsoB[4];
#pragma unroll
    for (int j = 0; j < 2; ++j) {
        int chunk = tid + 256 * j;           // 0..511
        int row = chunk >> 3, cs = chunk & 7;
        int cg = cs ^ (row & 7);
        offA[j]  = (size_t)(rowA0 + row) * KDIM + cg * 8;
        ldsoA[j] = chunk * 8;
    }
#pragma unroll
    for (int j = 0; j < 4; ++j) {
        int chunk = tid + 256 * j;           // 0..1023
        int row = chunk >> 3, cs = chunk & 7;
        int cg = cs ^ (row & 7);
        offB[j]  = (size_t)(rowB0 + row) * KDIM + cg * 8;
        ldsoB[j] = chunk * 8;
    }

    f32x4 acc[2][4];
#pragma unroll
    for (int mi = 0; mi < 2; ++mi)
#pragma unroll
        for (int ni = 0; ni < 4; ++ni)
            acc[mi][ni] = (f32x4){0.f, 0.f, 0.f, 0.f};

    // 6 global_load_lds per thread per STAGE -> vmcnt counts 6 per tile.
#define STAGE(buf, k0)                                                          \
    do {                                                                        \
        _Pragma("unroll")                                                       \
        for (int j = 0; j < 2; ++j) {                                           \
            __builtin_amdgcn_global_load_lds(                                   \
                (const __attribute__((address_space(1))) void*)(Rcur + offA[j] + (k0)), \
                (__attribute__((address_space(3))) void*)(As[buf] + ldsoA[j]),  \
                16, 0, 0);                                                      \
        }                                                                       \
        _Pragma("unroll")                                                       \
        for (int j = 0; j < 4; ++j) {                                           \
            __builtin_amdgcn_global_load_lds(                                   \
                (const __attribute__((address_space(1))) void*)(Wb + offB[j] + (k0)), \
                (__attribute__((address_space(3))) void*)(Bs[buf] + ldsoB[j]),  \
                16, 0, 0);                                                      \
        }                                                                       \
    } while (0)

#define COMPUTE(buf)                                                            \
    do {                                                                        \
        _Pragma("unroll")                                                       \
        for (int kk = 0; kk < 2; ++kk) {                                        \
            bf16x8 a[2], b[4];                                                  \
            _Pragma("unroll")                                                   \
            for (int mi = 0; mi < 2; ++mi) {                                    \
                int row = m0 + mi * 16 + lr;                                    \
                int slot = (kk * 4 + lk) ^ (row & 7);                           \
                a[mi] = *(const bf16x8*)(As[buf] + row * BK + slot * 8);        \
            }                                                                   \
            _Pragma("unroll")                                                   \
            for (int ni = 0; ni < 4; ++ni) {                                    \
                int row = n0 + ni * 16 + lr;                                    \
                int slot = (kk * 4 + lk) ^ (row & 7);                           \
                b[ni] = *(const bf16x8*)(Bs[buf] + row * BK + slot * 8);        \
            }                                                                   \
            _Pragma("unroll")                                                   \
            for (int mi = 0; mi < 2; ++mi)                                      \
                _Pragma("unroll")                                               \
                for (int ni = 0; ni < 4; ++ni)                                  \
                    acc[mi][ni] = __builtin_amdgcn_mfma_f32_16x16x32_bf16(      \
                        a[mi], b[ni], acc[mi][ni], 0, 0, 0);                    \
        }                                                                       \
    } while (0)

    // prologue: stage tiles 0 and 1 (12 loads in flight)
    STAGE(0, 0);
    STAGE(1, BK);

    int cur = 0, nxt = 1, far = 2;
    for (int t = 0; t < NT; ++t) {
        // wait for tile t's 6 loads (leave next tile's 6 in flight)
        if (t == NT - 1) {
            asm volatile("s_waitcnt vmcnt(0)" ::: "memory");
        } else {
            asm volatile("s_waitcnt vmcnt(6)" ::: "memory");
        }
        __builtin_amdgcn_s_barrier();
        // stage tile t+2 into `far` (readers of `far` at iter t-1 all passed
        // the barrier above, and their reads were consumed before it)
        if (t + 2 < NT) STAGE(far, (size_t)(t + 2) * BK);
        COMPUTE(cur);
        int tmp = cur; cur = nxt; nxt = far; far = tmp;
    }
#undef STAGE
#undef COMPUTE

    // Epilogue. C/D layout: col = lane&15, row = (lane>>4)*4 + reg.
    // One lane's 4 regs = c=0..3 of a single (b, n) -> contiguous float4 in h/x.
#pragma unroll
    for (int mi = 0; mi < 2; ++mi) {
        int i0 = rowA0 + m0 + mi * 16 + lk * 4;   // multiple of 4
        int b  = i0 >> 2;
#pragma unroll
        for (int ni = 0; ni < 4; ++ni) {
            int n = rowB0 + n0 + ni * 16 + lr;
            size_t hidx = (size_t)b * DLEN + (size_t)n * 4;
            f32x4 h4 = *(const f32x4*)(h + hidx);
            f32x4 x4 = *(const f32x4*)(x + hidx);
            f32x4 hn;
#pragma unroll
            for (int r = 0; r < 4; ++r) {
                float hv   = h4[r];
                float rho  = tanhf(hv);
                float drive = acc[mi][ni][r] + x4[r];
                float hnew = 0.9f * hv + 0.1f * (1.0f - rho * rho) * drive;
                hn[r] = hnew;
                Rnxt[(size_t)(i0 + r) * KDIM + n] = f32_to_bf16(tanhf(hnew));
            }
            *(f32x4*)(h + hidx) = hn;
            if (out) out[(size_t)b * NODES + n] = hn[0];
        }
    }
}

// ---------------------------------------------------------------------------
extern "C" void kernel_launch(void* const* d_in, const int* in_sizes, int n_in,
                              void* d_out, int out_size, void* d_ws, size_t ws_size,
                              hipStream_t stream) {
    const float* x = (const float*)d_in[0];   // (256, 16384) f32
    const float* W = (const float*)d_in[1];   // (4096, 4096) f32
    float* out = (float*)d_out;               // (256, 4096) f32

    char* ws = (char*)d_ws;
    // ws layout: Wb 32MB | R0 8MB | R1 8MB | h 16MB  (total 64MB)
    unsigned short* Wb = (unsigned short*)(ws);
    unsigned short* R0 = (unsigned short*)(ws + ((size_t)32 << 20));
    unsigned short* R1 = (unsigned short*)(ws + ((size_t)40 << 20));
    float*          h  = (float*)(ws + ((size_t)48 << 20));

    symw_kernel<<<dim3(64, 64), 256, 0, stream>>>(W, Wb);
    init_kernel<<<dim3(4096), 256, 0, stream>>>(x, h, R0);

    unsigned short* rc = R0;
    unsigned short* rn = R1;
    for (int s = 0; s < 10; ++s) {
        step_kernel<<<dim3(32, 16), 256, 0, stream>>>(
            rc, Wb, x, h, rn, (s == 9) ? out : nullptr);
        unsigned short* t = rc; rc = rn; rn = t;
    }
}

// Round 6
// 611.308 us; speedup vs baseline: 1.5995x; 1.0518x over previous
//
#include <hip/hip_runtime.h>
#include <hip/hip_bf16.h>

// Problem: CliffordEPBottleneck — 10 relaxation steps of
//   rho = tanh(h); drive = W_sym @ rho + x; h = 0.9h + 0.1(1-rho^2)*drive
// B=256, nodes=4096, COMP=4. Core: 10x GEMM (1024 x 4096 x 4096) bf16 MFMA.
//
// R6: A-operand bypasses LDS. rho is stored PACKED in MFMA fragment order
// (P[kc][mr][lane][8]), so each lane loads its A-fragment with one coalesced
// global_load_dwordx4 (L2/L3-resident, 8MB). Deletes 1/3 of ds_reads and the
// A-DMA (R5 model: LDS pipe ~98k cyc/CU = 62% busy = top pipe). B keeps
// ring-3 LDS + vmcnt(8) (4 B-stage + 4 A-loads per iter in flight).
// Epilogue repacks next rho via an LDS bounce (once per block).

#define NODES 4096
#define KDIM  4096
#define DLEN  16384
#define BM 64
#define BN 128
#define BK 64
#define NT (KDIM / BK)       // 64
#define PSTEP 65536          // packed elems per K-tile: 2 kc * 64 mr * 512

typedef __attribute__((ext_vector_type(8))) __bf16 bf16x8;
typedef __attribute__((ext_vector_type(4))) float  f32x4;

static __device__ __forceinline__ unsigned short f32_to_bf16(float f) {
    unsigned int u = __float_as_uint(f);
    u += 0x7fffu + ((u >> 16) & 1u);
    return (unsigned short)(u >> 16);
}

// ---------------------------------------------------------------------------
// Kernel 1: Wb[n][m] = bf16(0.5*(W[n][m] + W[m][n]))
// ---------------------------------------------------------------------------
__global__ __launch_bounds__(256)
void symw_kernel(const float* __restrict__ W, unsigned short* __restrict__ Wb) {
    __shared__ float Ta[64][64];
    __shared__ float Tb[64][65];
    const int tn = blockIdx.y, tm = blockIdx.x;
    const int c  = threadIdx.x & 63;
    const int r0 = threadIdx.x >> 6;
#pragma unroll
    for (int rr = 0; rr < 16; ++rr) {
        int r = r0 * 16 + rr;
        Ta[r][c] = W[(size_t)(tn * 64 + r) * 4096 + tm * 64 + c];
        Tb[r][c] = W[(size_t)(tm * 64 + r) * 4096 + tn * 64 + c];
    }
    __syncthreads();
#pragma unroll
    for (int rr = 0; rr < 16; ++rr) {
        int r = r0 * 16 + rr;
        float v = 0.5f * (Ta[r][c] + Tb[c][r]);
        Wb[(size_t)(tn * 64 + r) * 4096 + tm * 64 + c] = f32_to_bf16(v);
    }
}

// ---------------------------------------------------------------------------
// Kernel 2: h = x ; P0 = packed bf16(tanh(x)).
// Packed elem (i=b*4+c, k=m): kc=k>>5, mr=i>>4, lane=(i&15)|(((k>>3)&3)<<4),
// e=k&7; addr = (kc*64+mr)*512 + lane*8 + e.
// ---------------------------------------------------------------------------
__global__ __launch_bounds__(256)
void init_kernel(const float* __restrict__ x, float* __restrict__ h,
                 unsigned short* __restrict__ P0) {
    int idx = blockIdx.x * blockDim.x + threadIdx.x;   // over B*NODES = 1M
    int b = idx >> 12;
    int m = idx & 4095;
    f32x4 xv = *(const f32x4*)(x + (size_t)idx * 4);
    *(f32x4*)(h + (size_t)idx * 4) = xv;
    size_t base = ((size_t)(m >> 5) * 64 + (b >> 2)) * 512
                + (size_t)((m >> 3) & 3) * 128 + (m & 7);
#pragma unroll
    for (int c = 0; c < 4; ++c) {
        // lane = (b&3)*4+c + ((m>>3)&3)*16 ; addr = base + ((b&3)*4+c)*8
        P0[base + (size_t)((b & 3) * 4 + c) * 8] = f32_to_bf16(tanhf(xv[c]));
    }
}

// ---------------------------------------------------------------------------
// Kernel 3: one relaxation step.
// ---------------------------------------------------------------------------
__global__ __launch_bounds__(256, 2)
void step_kernel(const unsigned short* __restrict__ Pcur,
                 const unsigned short* __restrict__ Wb,
                 const float* __restrict__ x,
                 float* __restrict__ h,
                 unsigned short* __restrict__ Pnxt,
                 float* __restrict__ out) {
    __shared__ unsigned short Bs[3][BN * BK];   // 48 KB ring
    __shared__ unsigned short Tp[64][136];      // 17 KB pack bounce (padded)

    const int tid  = threadIdx.x;
    const int bx   = blockIdx.x;            // n-tile (0..31)
    const int by   = blockIdx.y;            // m-tile (0..15)
    const int rowB0 = bx * BN;

    const int w    = tid >> 6;
    const int lane = tid & 63;
    const int m0   = (w >> 1) * 32;
    const int n0   = (w & 1) * 64;
    const int lr   = lane & 15;
    const int lk   = lane >> 4;
    const int mr0  = by * 4 + (m0 >> 4);    // packed mr base for this wave

    // B staging offsets (4 chunks/thread), XOR-swizzled source
    size_t offB[4];
    int    ldsoB[4];
#pragma unroll
    for (int j = 0; j < 4; ++j) {
        int chunk = tid + 256 * j;
        int row = chunk >> 3, cs = chunk & 7;
        int cg = cs ^ (row & 7);
        offB[j]  = (size_t)(rowB0 + row) * KDIM + cg * 8;
        ldsoB[j] = chunk * 8;
    }
    // packed-A offsets: frag (mi, kk) at tile t lives at t*PSTEP + offa[mi][kk]
    size_t offa[2][2];
#pragma unroll
    for (int mi = 0; mi < 2; ++mi)
#pragma unroll
        for (int kk = 0; kk < 2; ++kk)
            offa[mi][kk] = (size_t)kk * 32768 + (size_t)(mr0 + mi) * 512 + lane * 8;

    f32x4 acc[2][4];
#pragma unroll
    for (int mi = 0; mi < 2; ++mi)
#pragma unroll
        for (int ni = 0; ni < 4; ++ni)
            acc[mi][ni] = (f32x4){0.f, 0.f, 0.f, 0.f};

    bf16x8 aA[2][2], aB[2][2];
    unsigned short* Bs0 = &Bs[0][0];

#define STAGE(buf, t)                                                           \
    do {                                                                        \
        _Pragma("unroll")                                                       \
        for (int j = 0; j < 4; ++j) {                                           \
            __builtin_amdgcn_global_load_lds(                                   \
                (const __attribute__((address_space(1))) void*)                \
                    (Wb + offB[j] + (size_t)(t) * BK),                          \
                (__attribute__((address_space(3))) void*)                      \
                    (Bs0 + (buf) * (BN * BK) + ldsoB[j]),                       \
                16, 0, 0);                                                      \
        }                                                                       \
    } while (0)

#define LOADA(aset, t)                                                          \
    do {                                                                        \
        const unsigned short* Pt = Pcur + (size_t)(t) * PSTEP;                  \
        _Pragma("unroll")                                                       \
        for (int mi = 0; mi < 2; ++mi)                                          \
            _Pragma("unroll")                                                   \
            for (int kk = 0; kk < 2; ++kk)                                      \
                aset[mi][kk] = *(const bf16x8*)(Pt + offa[mi][kk]);             \
    } while (0)

#define COMPUTE(buf, aset)                                                      \
    do {                                                                        \
        const unsigned short* Bb = Bs0 + (buf) * (BN * BK);                     \
        _Pragma("unroll")                                                       \
        for (int kk = 0; kk < 2; ++kk) {                                        \
            bf16x8 bfr[4];                                                      \
            _Pragma("unroll")                                                   \
            for (int ni = 0; ni < 4; ++ni) {                                    \
                int row = n0 + ni * 16 + lr;                                    \
                int slot = (kk * 4 + lk) ^ (row & 7);                           \
                bfr[ni] = *(const bf16x8*)(Bb + row * BK + slot * 8);           \
            }                                                                   \
            _Pragma("unroll")                                                   \
            for (int mi = 0; mi < 2; ++mi)                                      \
                _Pragma("unroll")                                               \
                for (int ni = 0; ni < 4; ++ni)                                  \
                    acc[mi][ni] = __builtin_amdgcn_mfma_f32_16x16x32_bf16(      \
                        aset[mi][kk], bfr[ni], acc[mi][ni], 0, 0, 0);           \
        }                                                                       \
    } while (0)

    // prologue: tiles 0,1 in flight (B-DMA + A-regs = 16 VMEM ops)
    STAGE(0, 0);
    LOADA(aA, 0);
    STAGE(1, 1);
    LOADA(aB, 1);

    int rc = 0, rn = 1, rf = 2;
    for (int tp = 0; tp < 31; ++tp) {
        const int t = tp * 2;
        // slot t (even): uses aA
        asm volatile("s_waitcnt vmcnt(8)" ::: "memory");
        __builtin_amdgcn_s_barrier();
        STAGE(rf, t + 2);
        COMPUTE(rc, aA);
        LOADA(aA, t + 2);
        { int z = rc; rc = rn; rn = rf; rf = z; }
        // slot t+1 (odd): uses aB
        asm volatile("s_waitcnt vmcnt(8)" ::: "memory");
        __builtin_amdgcn_s_barrier();
        STAGE(rf, t + 3);
        COMPUTE(rc, aB);
        LOADA(aB, t + 3);
        { int z = rc; rc = rn; rn = rf; rf = z; }
    }
    // t = 62
    asm volatile("s_waitcnt vmcnt(8)" ::: "memory");
    __builtin_amdgcn_s_barrier();
    COMPUTE(rc, aA);
    { int z = rc; rc = rn; rn = rf; rf = z; }
    // t = 63
    asm volatile("s_waitcnt vmcnt(0)" ::: "memory");
    __builtin_amdgcn_s_barrier();
    COMPUTE(rc, aB);
#undef STAGE
#undef LOADA
#undef COMPUTE

    // Epilogue. C/D: col=lane&15, row=(lane>>4)*4+reg. One lane's 4 regs =
    // c=0..3 of one (b,n) -> contiguous float4 in h/x. Stash rho_next in Tp.
    const int rowA0 = by * BM;
#pragma unroll
    for (int mi = 0; mi < 2; ++mi) {
        int il = m0 + mi * 16 + lk * 4;           // local i row (mult of 4)
        int i0 = rowA0 + il;
        int b  = i0 >> 2;
#pragma unroll
        for (int ni = 0; ni < 4; ++ni) {
            int nl = n0 + ni * 16 + lr;           // local n col
            int n  = rowB0 + nl;
            size_t hidx = (size_t)b * DLEN + (size_t)n * 4;
            f32x4 h4 = *(const f32x4*)(h + hidx);
            f32x4 x4 = *(const f32x4*)(x + hidx);
            f32x4 hn;
#pragma unroll
            for (int r = 0; r < 4; ++r) {
                float hv   = h4[r];
                float rho  = tanhf(hv);
                float drive = acc[mi][ni][r] + x4[r];
                float hnew = 0.9f * hv + 0.1f * (1.0f - rho * rho) * drive;
                hn[r] = hnew;
                Tp[il + r][nl] = f32_to_bf16(tanhf(hnew));
            }
            *(f32x4*)(h + hidx) = hn;
            if (out) out[(size_t)b * NODES + n] = hn[0];
        }
    }
    __syncthreads();
    // pack out: 16 chunks (kcl 0..3 x mrl 0..3), 4 per wave; each chunk =
    // 64 lanes x 16B coalesced store into Pnxt fragment order.
#pragma unroll
    for (int q = 0; q < 4; ++q) {
        int chunk = w * 4 + q;
        int kcl = chunk >> 2, mrl = chunk & 3;
        bf16x8 v = *(const bf16x8*)&Tp[mrl * 16 + lr][kcl * 32 + lk * 8];
        size_t po = ((size_t)(bx * 4 + kcl) * 64 + (by * 4 + mrl)) * 512
                  + (size_t)lane * 8;
        *(bf16x8*)(Pnxt + po) = v;
    }
}

// ---------------------------------------------------------------------------
extern "C" void kernel_launch(void* const* d_in, const int* in_sizes, int n_in,
                              void* d_out, int out_size, void* d_ws, size_t ws_size,
                              hipStream_t stream) {
    const float* x = (const float*)d_in[0];   // (256, 16384) f32
    const float* W = (const float*)d_in[1];   // (4096, 4096) f32
    float* out = (float*)d_out;               // (256, 4096) f32

    char* ws = (char*)d_ws;
    // ws layout: Wb 32MB | P0 8MB | P1 8MB | h 16MB
    unsigned short* Wb = (unsigned short*)(ws);
    unsigned short* P0 = (unsigned short*)(ws + ((size_t)32 << 20));
    unsigned short* P1 = (unsigned short*)(ws + ((size_t)40 << 20));
    float*          h  = (float*)(ws + ((size_t)48 << 20));

    symw_kernel<<<dim3(64, 64), 256, 0, stream>>>(W, Wb);
    init_kernel<<<dim3(4096), 256, 0, stream>>>(x, h, P0);

    unsigned short* pc = P0;
    unsigned short* pn = P1;
    for (int s = 0; s < 10; ++s) {
        step_kernel<<<dim3(32, 16), 256, 0, stream>>>(
            pc, Wb, x, h, pn, (s == 9) ? out : nullptr);
        unsigned short* t = pc; pc = pn; pn = t;
    }
}